// Round 6
// baseline (428.198 us; speedup 1.0000x reference)
//
#include <hip/hip_runtime.h>

typedef unsigned short u16;
typedef __bf16 bf16x8 __attribute__((ext_vector_type(8)));
typedef float f32x4 __attribute__((ext_vector_type(4)));

#define E_ 1024
#define T_ 2048
#define B_ 2
#define H_ 16
#define FF_ 4096
#define M_ 4096   // B*T

__device__ __forceinline__ u16 f2b(float f) {
    union { float f; unsigned u; } c; c.f = f;
    unsigned r = c.u + 0x7FFFu + ((c.u >> 16) & 1u);
    return (u16)(r >> 16);
}
// truncating f32->bf16 (1 op); used where downstream normalization cancels bias
__device__ __forceinline__ u16 f2bt(float f) {
    union { float f; unsigned u; } c; c.f = f;
    return (u16)(c.u >> 16);
}

// async global->LDS, 16B per lane; LDS dest = wave-uniform base + lane*16
__device__ __forceinline__ void gl16(const u16* g, u16* l) {
    __builtin_amdgcn_global_load_lds(
        (__attribute__((address_space(1))) void*)g,
        (__attribute__((address_space(3))) void*)l, 16, 0, 0);
}

template<int N> __device__ __forceinline__ void wait_vmcnt() {
    if constexpr (N == 2)      asm volatile("s_waitcnt vmcnt(2)" ::: "memory");
    else if constexpr (N == 3) asm volatile("s_waitcnt vmcnt(3)" ::: "memory");
    else if constexpr (N == 4) asm volatile("s_waitcnt vmcnt(4)" ::: "memory");
    else if constexpr (N == 8) asm volatile("s_waitcnt vmcnt(8)" ::: "memory");
    else                       asm volatile("s_waitcnt vmcnt(0)" ::: "memory");
}

// ---------------- fused weight/bias conversion + LN1 ----------------
__global__ __launch_bounds__(256) void cvt_ln(
        const float* __restrict__ Wq, const float* __restrict__ Wk,
        const float* __restrict__ Wv, const float* __restrict__ Wo,
        const float* __restrict__ W1, const float* __restrict__ W2,
        const float* __restrict__ bq, const float* __restrict__ bk,
        const float* __restrict__ bv,
        u16* __restrict__ WqkvB, u16* __restrict__ WoB,
        u16* __restrict__ W1B, u16* __restrict__ W2B,
        float* __restrict__ bqkv,
        const float* __restrict__ x, const float* __restrict__ g1,
        const float* __restrict__ b1v, u16* __restrict__ hB) {
    if (blockIdx.x < 1024) {
        int row = blockIdx.x * 4 + (threadIdx.x >> 6);
        int t = threadIdx.x & 63;
        const float* xr = x + (size_t)row * E_;
        float v[16];
        float sum = 0.f, ss = 0.f;
#pragma unroll
        for (int c = 0; c < 4; c++) {
            float4 f = *(const float4*)&xr[c * 256 + t * 4];
            v[c * 4 + 0] = f.x; v[c * 4 + 1] = f.y; v[c * 4 + 2] = f.z; v[c * 4 + 3] = f.w;
            sum += f.x + f.y + f.z + f.w;
            ss += f.x * f.x + f.y * f.y + f.z * f.z + f.w * f.w;
        }
#pragma unroll
        for (int d = 32; d; d >>= 1) {
            sum += __shfl_xor(sum, d);
            ss  += __shfl_xor(ss, d);
        }
        float mu = sum * (1.f / E_);
        float var = ss * (1.f / E_) - mu * mu;
        float rs = rsqrtf(var + 1e-5f);
#pragma unroll
        for (int c = 0; c < 4; c++) {
            int idx = c * 256 + t * 4;
            float4 g4 = *(const float4*)&g1[idx];
            float4 b4 = *(const float4*)&b1v[idx];
            ushort4 o;
            o.x = f2b((v[c * 4 + 0] - mu) * rs * g4.x + b4.x);
            o.y = f2b((v[c * 4 + 1] - mu) * rs * g4.y + b4.y);
            o.z = f2b((v[c * 4 + 2] - mu) * rs * g4.z + b4.z);
            o.w = f2b((v[c * 4 + 3] - mu) * rs * g4.w + b4.w);
            *(ushort4*)&hB[(size_t)row * E_ + idx] = o;
        }
        return;
    }
    int i = (blockIdx.x - 1024) * 256 + threadIdx.x;
    if (i >= 3146496) return;
    if (i >= 3145728) {             // biases (fp32 copy)
        int j = i - 3145728;        // 0..767
        const float* s = (j < 256) ? bq : (j < 512) ? bk : bv;
        int jj = j & 255;
        *(float4*)&bqkv[j * 4] = *(const float4*)&s[jj * 4];
        return;
    }
    const float* src; u16* dst; int j;
    if (i < 786432) {
        src = (i < 262144) ? Wq : (i < 524288) ? Wk : Wv;
        j = i & 262143;
        dst = WqkvB + (i >> 18) * (E_ * E_);
    } else if (i < 1048576) { j = i - 786432;  src = Wo; dst = WoB; }
    else if (i < 2097152)   { j = i - 1048576; src = W1; dst = W1B; }
    else                    { j = i - 2097152; src = W2; dst = W2B; }
    float4 f = *(const float4*)&src[j * 4];
    ushort4 o;
    o.x = f2b(f.x); o.y = f2b(f.y); o.z = f2b(f.z); o.w = f2b(f.w);
    *(ushort4*)&dst[j * 4] = o;
}

// ---------------- LayerNorm: 1 wave per row of 1024 ----------------
__global__ __launch_bounds__(64) void ln_fwd(u16* __restrict__ out, const float* __restrict__ x,
                                             const float* __restrict__ g, const float* __restrict__ bta) {
    int row = blockIdx.x;
    int t = threadIdx.x;
    const float* xr = x + (size_t)row * E_;
    float v[16];
    float sum = 0.f, ss = 0.f;
#pragma unroll
    for (int c = 0; c < 4; c++) {
        float4 f = *(const float4*)&xr[c * 256 + t * 4];
        v[c * 4 + 0] = f.x; v[c * 4 + 1] = f.y; v[c * 4 + 2] = f.z; v[c * 4 + 3] = f.w;
        sum += f.x + f.y + f.z + f.w;
        ss += f.x * f.x + f.y * f.y + f.z * f.z + f.w * f.w;
    }
#pragma unroll
    for (int d = 32; d; d >>= 1) {
        sum += __shfl_xor(sum, d);
        ss  += __shfl_xor(ss, d);
    }
    float mu = sum * (1.f / E_);
    float var = ss * (1.f / E_) - mu * mu;
    float rs = rsqrtf(var + 1e-5f);
#pragma unroll
    for (int c = 0; c < 4; c++) {
        int idx = c * 256 + t * 4;
        float4 g4 = *(const float4*)&g[idx];
        float4 b4 = *(const float4*)&bta[idx];
        ushort4 o;
        o.x = f2b((v[c * 4 + 0] - mu) * rs * g4.x + b4.x);
        o.y = f2b((v[c * 4 + 1] - mu) * rs * g4.y + b4.y);
        o.z = f2b((v[c * 4 + 2] - mu) * rs * g4.z + b4.z);
        o.w = f2b((v[c * 4 + 3] - mu) * rs * g4.w + b4.w);
        *(ushort4*)&out[(size_t)row * E_ + idx] = o;
    }
}

// ============ 256x256 4-phase MFMA GEMM, counted-vmcnt (T1+T2+T4+T5) ============
// C[M,N] = A[M,K] * Bt[N,K]^T. 512 thr = 8 waves (2 wm x 4 wn), wave tile 128x64.
// BK=64. LDS: A TRIPLE-buffered (3x32KB), B double-buffered (2x32KB) = 160 KB.
// The 3-deep A is what makes a COUNTED boundary wait possible: A(t+2) stages
// during tile t (its slot was last read at t-1), so at each tile boundary only
// the 8 oldest loads (A(t+1)+B(t+1)) must land -> s_waitcnt vmcnt(4), leaving
// A(t+2)'s 4 loads in flight. Never vmcnt(0) in steady state; each load has
// 4-7 phases (~2800+ cyc) of latency cover. ONE barrier per phase (4/tile):
// no pre-MFMA barrier, no explicit lgkmcnt (compiler interleaves lgkm waits).
// In-flight induction (verified): after boundary(t) = A(t+2)x4; +B(t+1)x4 @ph0,
// +A(t+3)x4 @ph1/ph2 = 12; boundary waits oldest 8 -> vmcnt(4).
// Edges: prologue stages tiles 0,1 then vmcnt(8); t=nk-2 -> vmcnt(0).
// LDS swizzle (T2): element (row,col) at (row*64+col)^((row&7)<<3); gl16 dest
// linear, global source chunk pre-swizzled (rule 21). Bank conflicts = 0 (R4/R5).
template<int QKV, int SPLIT>
__global__ __launch_bounds__(512, 2) void gemm256(
        const u16* __restrict__ A, const u16* __restrict__ Bt,
        const float* __restrict__ bias, const float* __restrict__ residual,
        float* __restrict__ outF, float* __restrict__ oP1,
        float* __restrict__ oP2, float* __restrict__ oP3,
        u16* __restrict__ outB, u16* __restrict__ outVt,
        int N, int K, int ldk, int relu) {
    __shared__ __align__(16) u16 As[3][256 * 64];
    __shared__ __align__(16) u16 Bs[2][256 * 64];
    int tid = threadIdx.x;
    int bx = blockIdx.x, by = blockIdx.y;
    {   // bijective XCD-chunked swizzle within (x,y) plane; nwg % 8 == 0 everywhere
        int gx = gridDim.x;
        int nwg = gx * (int)gridDim.y, cpx = nwg >> 3;
        int lin = by * gx + bx;
        int wv = (lin & 7) * cpx + (lin >> 3);
        bx = wv % gx; by = wv / gx;
    }
    int m0 = by * 256, n0 = bx * 256;
    int kz = blockIdx.z;
    int koff = kz * K;
    int w = tid >> 6, lane = tid & 63;
    int wm = w >> 2, wn = w & 3;
    int r16 = lane & 15, kg = lane >> 4;
    int sw = (r16 & 7) << 3;            // read-side element XOR (row&7)<<3

    // staging: thread -> (row = 64*stripe + (tid>>3), chunk (tid&7), 8 elems)
    int srow = tid >> 3;
    int schunk = (tid & 7) ^ (srow & 7);   // pre-swizzled global source chunk
    const u16* gAs = A + (size_t)(m0 + srow) * ldk + koff + schunk * 8;
    const u16* gBs = Bt + (size_t)(n0 + srow) * ldk + koff + schunk * 8;
    size_t rstep = (size_t)64 * ldk;

    f32x4 acc[8][4] = {};
    const int nk = K >> 6;

    // stripe r = rows 64r..64r+63 (8 KB); one gl16/thread per stripe
    auto stA = [&](int kt, int slot, int r0, int r1) {
        const u16* g = gAs + kt * 64;
        u16* l = &As[slot][0] + tid * 8;
        gl16(g + (size_t)r0 * rstep, l + r0 * 4096);
        gl16(g + (size_t)r1 * rstep, l + r1 * 4096);
    };
    auto stB = [&](int kt, int slot, int r0, int r1) {
        const u16* g = gBs + kt * 64;
        u16* l = &Bs[slot][0] + tid * 8;
        gl16(g + (size_t)r0 * rstep, l + r0 * 4096);
        gl16(g + (size_t)r1 * rstep, l + r1 * 4096);
    };

    // prologue: tiles 0 (oldest) and 1; wait tile 0 (oldest 8) -> vmcnt(8)
    stB(0, 0, 0, 1); stB(0, 0, 2, 3); stA(0, 0, 0, 2); stA(0, 0, 1, 3);
    stB(1, 1, 0, 1); stB(1, 1, 2, 3); stA(1, 1, 0, 2); stA(1, 1, 1, 3);
    wait_vmcnt<8>();
    __builtin_amdgcn_s_barrier();
    asm volatile("" ::: "memory");

    int ca = 0;     // A slot of tile t (t % 3)
    int sa2 = 2;    // A slot of tile t+2 ((t+2) % 3)
    for (int t = 0; t < nk; t++) {
        int cbB = t & 1;
        const bool pf1 = (t + 1 < nk), pf2 = (t + 2 < nk);
        bf16x8 bfr[4];
#pragma unroll
        for (int ph = 0; ph < 4; ph++) {
            const int kk = ph >> 1, mh = ph & 1;
            // ---- stage issue first (early VMEM) ----
            if (ph == 0 && t && pf1) {          // B(t+1): slot read last at t-1
                stB(t + 1, cbB ^ 1, 0, 1); stB(t + 1, cbB ^ 1, 2, 3);
            }
            if (ph == 1 && pf2) stA(t + 2, sa2, 0, 2);   // A(t+2): slot read last at t-1
            if (ph == 2 && pf2) stA(t + 2, sa2, 1, 3);
            // ---- ds reads (compiler inserts fine-grained lgkm waits) ----
            int ce = kk * 32 + kg * 8;          // element col offset
            if (mh == 0) {
#pragma unroll
                for (int nf = 0; nf < 4; nf++) {
                    int row = wn * 64 + nf * 16 + r16;
                    bfr[nf] = *(const bf16x8*)&Bs[cbB][(row * 64 + ce) ^ sw];
                }
            }
            bf16x8 af[4];
#pragma unroll
            for (int i = 0; i < 4; i++) {
                int row = wm * 128 + (mh * 4 + i) * 16 + r16;
                af[i] = *(const bf16x8*)&As[ca][(row * 64 + ce) ^ sw];
            }
            __builtin_amdgcn_s_setprio(1);
#pragma unroll
            for (int i = 0; i < 4; i++)
#pragma unroll
                for (int nf = 0; nf < 4; nf++)
                    acc[mh * 4 + i][nf] = __builtin_amdgcn_mfma_f32_16x16x32_bf16(
                        af[i], bfr[nf], acc[mh * 4 + i][nf], 0, 0, 0);
            __builtin_amdgcn_s_setprio(0);
            // ---- boundary: counted wait (oldest 8 = tile t+1 data); never 0 mid-loop
            if (ph == 3) {
                if (pf2) wait_vmcnt<4>();
                else     wait_vmcnt<0>();
            }
            __builtin_amdgcn_s_barrier();
            asm volatile("" ::: "memory");
        }
        ca = (ca == 2) ? 0 : ca + 1;
        sa2 = (sa2 == 2) ? 0 : sa2 + 1;
    }

#pragma unroll
    for (int mf = 0; mf < 8; mf++) {
#pragma unroll
        for (int nf = 0; nf < 4; nf++) {
            int gm = m0 + wm * 128 + mf * 16 + kg * 4;
            int gn = n0 + wn * 64 + nf * 16 + r16;
            float bv = bias[gn];
            if (QKV) {
                if (gn < 2048) {
                    // Q prescale: 1/sqrt(64) * log2(e) (attn softmax in exp2 domain)
                    float scl = (gn < 1024) ? 0.18033688f : 1.0f;
#pragma unroll
                    for (int r = 0; r < 4; r++)
                        outB[(size_t)(gm + r) * 2048 + gn] = f2b((acc[mf][nf][r] + bv) * scl);
                } else {
                    int bq_ = gm >> 11, tq = gm & 2047, d = gn - 2048;
                    ushort4 ov;
                    ov.x = f2b(acc[mf][nf][0] + bv);
                    ov.y = f2b(acc[mf][nf][1] + bv);
                    ov.z = f2b(acc[mf][nf][2] + bv);
                    ov.w = f2b(acc[mf][nf][3] + bv);
                    *(ushort4*)&outVt[((size_t)(bq_ * 1024 + d)) * 2048 + tq] = ov;
                }
            } else if (SPLIT) {
                float* po = (kz == 1) ? oP1 : (kz == 2) ? oP2 : oP3;
#pragma unroll
                for (int r = 0; r < 4; r++) {
                    size_t off = (size_t)(gm + r) * N + gn;
                    if (kz == 0) {
                        float v = acc[mf][nf][r] + bv;
                        if (residual) v += residual[off];
                        outF[off] = v;
                    } else {
                        po[off] = acc[mf][nf][r];
                    }
                }
            } else {
#pragma unroll
                for (int r = 0; r < 4; r++) {
                    float v = acc[mf][nf][r] + bv;
                    if (relu) v = fmaxf(v, 0.f);
                    outB[(size_t)(gm + r) * N + gn] = f2b(v);
                }
            }
        }
    }
}

// ---------------- bf16 MFMA GEMM, 3-stage counted-vmcnt pipeline ----------------
// (kept for the out-projection: grid too small for the 256^2 kernel)
template<int BM, int BN>
__global__ __launch_bounds__(256) void gemm_bt(
        const u16* __restrict__ A, const u16* __restrict__ Bt,
        const float* __restrict__ bias, const float* __restrict__ residual,
        float* __restrict__ outF, float* __restrict__ oP1,
        float* __restrict__ oP2, float* __restrict__ oP3,
        u16* __restrict__ outB, u16* __restrict__ outVt,
        int M, int N, int K, int ldk, int relu, int qkvmode, int swz) {
    constexpr int MT = BM / 32, NT = BN / 32;
    constexpr int LA = BM / 64, LB = BN / 64;   // gl16 issues per wave per K-step
    __shared__ __align__(16) u16 As[3][BM * 32];
    __shared__ __align__(16) u16 Bs[3][BN * 32];
    int tid = threadIdx.x;
    int bx = blockIdx.x, by = blockIdx.y;
    if (swz) {
        int gx = gridDim.x;
        int nwg = gx * gridDim.y;
        int lin = by * gx + bx;
        int wv = (lin & 7) * (nwg >> 3) + (lin >> 3);
        bx = wv % gx; by = wv / gx;
    }
    int m0 = by * BM, n0 = bx * BN;
    int kz = blockIdx.z;
    int koff = kz * K;
    int wave = tid >> 6, lane = tid & 63;
    int wm = wave & 1, wn = wave >> 1;
    int r16 = lane & 15, kg = lane >> 4;

    const u16* gA = A + (size_t)(m0 + wave * (BM / 4) + (lane >> 2)) * ldk + koff + (lane & 3) * 8;
    const u16* gB = Bt + (size_t)(n0 + wave * (BN / 4) + (lane >> 2)) * ldk + koff + (lane & 3) * 8;
    size_t row16 = (size_t)16 * ldk;
    int aoff = wave * (BM / 4) * 32;
    int boff = wave * (BN / 4) * 32;

    f32x4 acc[MT][NT] = {};

    const int nk = K >> 5;

    auto issue = [&](int kt, int buf) {
        int k1 = kt << 5;
        gl16(gA + k1, As[buf] + aoff);
        if (LA == 2) gl16(gA + k1 + row16, As[buf] + aoff + 512);
        gl16(gB + k1, Bs[buf] + boff);
        if (LB == 2) gl16(gB + k1 + row16, Bs[buf] + boff + 512);
    };

    auto compute = [&](int cb) {
        bf16x8 af[MT], bfr[NT];
#pragma unroll
        for (int mt = 0; mt < MT; mt++)
            af[mt] = *(const bf16x8*)&As[cb][(wm * (BM / 2) + mt * 16 + r16) * 32 + kg * 8];
#pragma unroll
        for (int nt = 0; nt < NT; nt++)
            bfr[nt] = *(const bf16x8*)&Bs[cb][(wn * (BN / 2) + nt * 16 + r16) * 32 + kg * 8];
#pragma unroll
        for (int mt = 0; mt < MT; mt++)
#pragma unroll
            for (int nt = 0; nt < NT; nt++)
                acc[mt][nt] = __builtin_amdgcn_mfma_f32_16x16x32_bf16(af[mt], bfr[nt], acc[mt][nt], 0, 0, 0);
    };

    issue(0, 0);
    issue(1, 1);

    int cur = 0;
    for (int ks = 0; ks < nk - 1; ks++) {
        wait_vmcnt<LA + LB>();
        __builtin_amdgcn_s_barrier();
        asm volatile("" ::: "memory");
        if (ks + 2 < nk) {
            int p2 = cur ? cur - 1 : 2;
            issue(ks + 2, p2);
        }
        compute(cur);
        cur = (cur < 2) ? cur + 1 : 0;
    }
    asm volatile("s_waitcnt vmcnt(0)" ::: "memory");
    __builtin_amdgcn_s_barrier();
    asm volatile("" ::: "memory");
    compute(cur);

#pragma unroll
    for (int mt = 0; mt < MT; mt++) {
#pragma unroll
        for (int nt = 0; nt < NT; nt++) {
            int gm = m0 + wm * (BM / 2) + mt * 16 + kg * 4;
            int gn = n0 + wn * (BN / 2) + nt * 16 + r16;
            float bv = bias[gn];
            if (qkvmode) {
                if (gn < 2048) {
                    float scl = (gn < 1024) ? 0.18033688f : 1.0f;
#pragma unroll
                    for (int r = 0; r < 4; r++)
                        outB[(size_t)(gm + r) * 2048 + gn] = f2b((acc[mt][nt][r] + bv) * scl);
                } else {
                    int bq_ = gm >> 11, tq = gm & 2047, d = gn - 2048;
                    ushort4 ov;
                    ov.x = f2b(acc[mt][nt][0] + bv);
                    ov.y = f2b(acc[mt][nt][1] + bv);
                    ov.z = f2b(acc[mt][nt][2] + bv);
                    ov.w = f2b(acc[mt][nt][3] + bv);
                    *(ushort4*)&outVt[((size_t)(bq_ * 1024 + d)) * 2048 + tq] = ov;
                }
            } else if (oP1) {
                float* po = (kz == 1) ? oP1 : (kz == 2) ? oP2 : oP3;
#pragma unroll
                for (int r = 0; r < 4; r++) {
                    size_t off = (size_t)(gm + r) * N + gn;
                    if (kz == 0) {
                        float v = acc[mt][nt][r] + bv;
                        if (residual) v += residual[off];
                        outF[off] = v;
                    } else {
                        po[off] = acc[mt][nt][r];
                    }
                }
            } else {
#pragma unroll
                for (int r = 0; r < 4; r++) {
                    float v = acc[mt][nt][r] + bv;
                    size_t off = (size_t)(gm + r) * N + gn;
                    if (residual) v += residual[off];
                    if (relu) v = fmaxf(v, 0.f);
                    if (outF) outF[off] = v;
                    else outB[off] = f2b(v);
                }
            }
        }
    }
}

// split-K combine: d += a + b + c  (bias+residual already folded into d by kz0 pass)
__global__ __launch_bounds__(256) void addf3(float* __restrict__ d, const float* __restrict__ a,
                                             const float* __restrict__ b, const float* __restrict__ c) {
    size_t i = ((size_t)blockIdx.x * 256 + threadIdx.x) * 4;
    float4 vd = *(float4*)&d[i];
    float4 va = *(const float4*)&a[i];
    float4 vb = *(const float4*)&b[i];
    float4 vc = *(const float4*)&c[i];
    vd.x += va.x + vb.x + vc.x;
    vd.y += va.y + vb.y + vc.y;
    vd.z += va.z + vb.z + vc.z;
    vd.w += va.w + vb.w + vc.w;
    *(float4*)&d[i] = vd;
}

// ---------------- MFMA flash attention (bf16, causal, FIXED-SHIFT exp2 softmax) -----
#define AST 68   // 34 dw stride: bank-conflict-free for all access patterns here
__global__ __launch_bounds__(256) void attn_mfma(
        const u16* __restrict__ qk, const u16* __restrict__ vt,
        u16* __restrict__ out) {
    __shared__ __align__(16) u16 Ks[2][64 * AST];  // K[key][d]
    __shared__ __align__(16) u16 Vs[2][64 * AST];  // Vt[d][key]
    __shared__ __align__(16) u16 Ps[4][16 * AST];  // per-wave P[q][key]

    int bz = blockIdx.x;
    int h  = bz & 15;
    int b  = (bz >> 4) & 1;
    int qt = bz >> 5;

    int tid = threadIdx.x;
    int w = tid >> 6, lane = tid & 63;
    int g = lane >> 4, l16 = lane & 15;

    int qrow = qt * 64 + w * 16 + l16;
    bf16x8 qf[2];
    qf[0] = *(const bf16x8*)&qk[(size_t)(b * T_ + qrow) * 2048 + h * 64 + g * 8];
    qf[1] = *(const bf16x8*)&qk[(size_t)(b * T_ + qrow) * 2048 + h * 64 + 32 + g * 8];

    f32x4 o[4] = {};
    f32x4 lp = {0.f, 0.f, 0.f, 0.f};

    int r1 = tid >> 3, col1 = (tid & 7) * 8;
    const u16* gK = qk + (size_t)(b * T_) * 2048 + 1024 + h * 64;
    const u16* gV = vt + (size_t)(b * 1024 + h * 64) * 2048;

    uint4 kr1 = *(const uint4*)&gK[(size_t)r1 * 2048 + col1];
    uint4 kr2 = *(const uint4*)&gK[(size_t)(r1 + 32) * 2048 + col1];
    uint4 vr1 = *(const uint4*)&gV[(size_t)r1 * 2048 + col1];
    uint4 vr2 = *(const uint4*)&gV[(size_t)(r1 + 32) * 2048 + col1];

    for (int t = 0; t <= qt; t++) {
        int cur = t & 1;
        *(uint4*)&Ks[cur][r1 * AST + col1] = kr1;
        *(uint4*)&Ks[cur][(r1 + 32) * AST + col1] = kr2;
        *(uint4*)&Vs[cur][r1 * AST + col1] = vr1;
        *(uint4*)&Vs[cur][(r1 + 32) * AST + col1] = vr2;
        __syncthreads();
        if (t < qt) {
            int j1 = (t + 1) * 64;
            kr1 = *(const uint4*)&gK[(size_t)(j1 + r1) * 2048 + col1];
            kr2 = *(const uint4*)&gK[(size_t)(j1 + r1 + 32) * 2048 + col1];
            vr1 = *(const uint4*)&gV[(size_t)r1 * 2048 + j1 + col1];
            vr2 = *(const uint4*)&gV[(size_t)(r1 + 32) * 2048 + j1 + col1];
        }

        f32x4 s[4];
#pragma unroll
        for (int nt = 0; nt < 4; nt++) {
            f32x4 c16 = {-16.f, -16.f, -16.f, -16.f};
            bf16x8 k0 = *(const bf16x8*)&Ks[cur][(nt * 16 + l16) * AST + g * 8];
            bf16x8 k1 = *(const bf16x8*)&Ks[cur][(nt * 16 + l16) * AST + 32 + g * 8];
            s[nt] = __builtin_amdgcn_mfma_f32_16x16x32_bf16(qf[0], k0, c16, 0, 0, 0);
            s[nt] = __builtin_amdgcn_mfma_f32_16x16x32_bf16(qf[1], k1, s[nt], 0, 0, 0);
        }

        if (t == qt) {
            int j0 = t * 64;
#pragma unroll
            for (int nt = 0; nt < 4; nt++) {
                int key = j0 + nt * 16 + l16;
#pragma unroll
                for (int r = 0; r < 4; r++) {
                    int q = qt * 64 + w * 16 + g * 4 + r;
                    if (key > q) s[nt][r] = -INFINITY;
                }
            }
        }

#pragma unroll
        for (int nt = 0; nt < 4; nt++)
#pragma unroll
            for (int r = 0; r < 4; r++) {
                float p = exp2f(s[nt][r]);
                lp[r] += p;
                Ps[w][(g * 4 + r) * AST + nt * 16 + l16] = f2bt(p);
            }

#pragma unroll
        for (int kf = 0; kf < 2; kf++) {
            bf16x8 pf = *(const bf16x8*)&Ps[w][l16 * AST + kf * 32 + g * 8];
#pragma unroll
            for (int nt = 0; nt < 4; nt++) {
                bf16x8 vf = *(const bf16x8*)&Vs[cur][(nt * 16 + l16) * AST + kf * 32 + g * 8];
                o[nt] = __builtin_amdgcn_mfma_f32_16x16x32_bf16(pf, vf, o[nt], 0, 0, 0);
            }
        }
    }

#pragma unroll
    for (int x = 1; x <= 8; x <<= 1)
#pragma unroll
        for (int r = 0; r < 4; r++)
            lp[r] += __shfl_xor(lp[r], x);

    float inv[4];
#pragma unroll
    for (int r = 0; r < 4; r++) inv[r] = 1.f / lp[r];
    int qg = qt * 64 + w * 16 + g * 4;
#pragma unroll
    for (int nt = 0; nt < 4; nt++)
#pragma unroll
        for (int r = 0; r < 4; r++)
            out[(size_t)(b * T_ + qg + r) * E_ + h * 64 + nt * 16 + l16] =
                f2b(o[nt][r] * inv[r]);
}

extern "C" void kernel_launch(void* const* d_in, const int* in_sizes, int n_in,
                              void* d_out, int out_size, void* d_ws, size_t ws_size,
                              hipStream_t stream) {
    const float* x    = (const float*)d_in[0];
    const float* Wq   = (const float*)d_in[1];
    const float* bq   = (const float*)d_in[2];
    const float* Wk   = (const float*)d_in[3];
    const float* bk   = (const float*)d_in[4];
    const float* Wv   = (const float*)d_in[5];
    const float* bv   = (const float*)d_in[6];
    const float* Wo   = (const float*)d_in[7];
    const float* bo   = (const float*)d_in[8];
    const float* W1   = (const float*)d_in[9];
    const float* b1   = (const float*)d_in[10];
    const float* W2   = (const float*)d_in[11];
    const float* b2   = (const float*)d_in[12];
    const float* ln1g = (const float*)d_in[13];
    const float* ln1b = (const float*)d_in[14];
    const float* ln2g = (const float*)d_in[15];
    const float* ln2b = (const float*)d_in[16];

    char* ws = (char*)d_ws;
    size_t off = 0;
    auto alloc = [&](size_t bytes) { char* p = ws + off; off += (bytes + 255) & ~(size_t)255; return p; };

    u16*   hB    = (u16*)  alloc((size_t)M_ * E_ * 2);        // LN1 out bf16
    u16*   WqkvB = (u16*)  alloc((size_t)3 * E_ * E_ * 2);    // packed q,k,v weights bf16
    u16*   WoB   = (u16*)  alloc((size_t)E_ * E_ * 2);
    u16*   W1B   = (u16*)  alloc((size_t)FF_ * E_ * 2);
    u16*   W2B   = (u16*)  alloc((size_t)E_ * FF_ * 2);
    float* bqkv  = (float*)alloc(3 * E_ * 4);
    u16*   qkB   = (u16*)  alloc((size_t)M_ * 2 * E_ * 2);    // bf16 [M,2048], Q prescaled
    u16*   vtG   = (u16*)  alloc((size_t)M_ * E_ * 2);        // bf16 V^T [B*1024, 2048]
    u16*   attnB = (u16*)  alloc((size_t)M_ * E_ * 2);        // attention out bf16
    float* x2    = (float*)alloc((size_t)M_ * E_ * 4);        // after out-proj + residual
    u16*   h2B   = (u16*)  alloc((size_t)M_ * E_ * 2);        // LN2 out bf16
    u16*   rB    = (u16*)  alloc((size_t)M_ * FF_ * 2);       // relu(ff1) bf16
    float* P1    = (float*)alloc((size_t)M_ * E_ * 4);        // FF2 split-K partial (kz=1)
    // kz=2,3 partials alias workspace that is dead by FF2 time:
    float* P2 = (float*)qkB;    // 16 MB, dead after attn
    float* P3 = (float*)ws;     // hB+WqkvB+WoB = 16 MB, dead after Wo-proj

    // fused weight/bias conversion + LN1 (one launch)
    cvt_ln<<<1024 + 12291, 256, 0, stream>>>(Wq, Wk, Wv, Wo, W1, W2, bq, bk, bv,
                                             WqkvB, WoB, W1B, W2B, bqkv,
                                             x, ln1g, ln1b, hB);

    // fused QKV projection: [4096,1024] x [3072,1024]^T  (192 blocks, counted pipeline)
    gemm256<1, 0><<<dim3(3 * E_ / 256, M_ / 256), 512, 0, stream>>>(
        hB, WqkvB, bqkv, nullptr, nullptr, nullptr, nullptr, nullptr,
        qkB, vtG, 3 * E_, E_, E_, 0);

    // flash attention
    attn_mfma<<<B_ * H_ * (T_ / 64), 256, 0, stream>>>(qkB, vtG, attnB);

    // out projection + residual: x2 = x + attn @ Wo^T + bo  (512 blocks, 2/CU)
    gemm_bt<64, 128><<<dim3(E_ / 128, M_ / 64), 256, 0, stream>>>(
        attnB, WoB, bo, x, x2, nullptr, nullptr, nullptr, nullptr, nullptr,
        M_, E_, E_, E_, 0, 0, 0);

    // LN2
    ln_fwd<<<M_, 64, 0, stream>>>(h2B, x2, ln2g, ln2b);

    // FF1 + relu -> bf16  (256 blocks = 1/CU)
    gemm256<0, 0><<<dim3(FF_ / 256, M_ / 256), 512, 0, stream>>>(
        h2B, W1B, b1, nullptr, nullptr, nullptr, nullptr, nullptr,
        rB, nullptr, FF_, E_, E_, 1);

    // FF2 split-K=4: grid (4,16,4) = 256 blocks, K=1024/plane (ldk=4096)
    gemm256<0, 1><<<dim3(E_ / 256, M_ / 256, 4), 512, 0, stream>>>(
        rB, W2B, b2, x2, (float*)d_out, P1, P2, P3,
        nullptr, nullptr, E_, FF_ / 4, FF_, 0);

    // combine: d_out += P1 + P2 + P3
    addf3<<<(M_ * E_) / (256 * 4), 256, 0, stream>>>((float*)d_out, P1, P2, P3);
}

// Round 7
// 389.085 us; speedup vs baseline: 1.1005x; 1.1005x over previous
//
#include <hip/hip_runtime.h>

typedef unsigned short u16;
typedef __bf16 bf16x8 __attribute__((ext_vector_type(8)));
typedef float f32x4 __attribute__((ext_vector_type(4)));

#define E_ 1024
#define T_ 2048
#define B_ 2
#define H_ 16
#define FF_ 4096
#define M_ 4096   // B*T

__device__ __forceinline__ u16 f2b(float f) {
    union { float f; unsigned u; } c; c.f = f;
    unsigned r = c.u + 0x7FFFu + ((c.u >> 16) & 1u);
    return (u16)(r >> 16);
}
// truncating f32->bf16 (1 op); used where downstream normalization cancels bias
__device__ __forceinline__ u16 f2bt(float f) {
    union { float f; unsigned u; } c; c.f = f;
    return (u16)(c.u >> 16);
}

// async global->LDS, 16B per lane; LDS dest = wave-uniform base + lane*16
__device__ __forceinline__ void gl16(const u16* g, u16* l) {
    __builtin_amdgcn_global_load_lds(
        (__attribute__((address_space(1))) void*)g,
        (__attribute__((address_space(3))) void*)l, 16, 0, 0);
}

template<int N> __device__ __forceinline__ void wait_vmcnt() {
    if constexpr (N == 2)      asm volatile("s_waitcnt vmcnt(2)" ::: "memory");
    else if constexpr (N == 3) asm volatile("s_waitcnt vmcnt(3)" ::: "memory");
    else if constexpr (N == 4) asm volatile("s_waitcnt vmcnt(4)" ::: "memory");
    else                       asm volatile("s_waitcnt vmcnt(0)" ::: "memory");
}

// ---------------- fused weight/bias conversion + LN1 ----------------
__global__ __launch_bounds__(256) void cvt_ln(
        const float* __restrict__ Wq, const float* __restrict__ Wk,
        const float* __restrict__ Wv, const float* __restrict__ Wo,
        const float* __restrict__ W1, const float* __restrict__ W2,
        const float* __restrict__ bq, const float* __restrict__ bk,
        const float* __restrict__ bv,
        u16* __restrict__ WqkvB, u16* __restrict__ WoB,
        u16* __restrict__ W1B, u16* __restrict__ W2B,
        float* __restrict__ bqkv,
        const float* __restrict__ x, const float* __restrict__ g1,
        const float* __restrict__ b1v, u16* __restrict__ hB) {
    if (blockIdx.x < 1024) {
        int row = blockIdx.x * 4 + (threadIdx.x >> 6);
        int t = threadIdx.x & 63;
        const float* xr = x + (size_t)row * E_;
        float v[16];
        float sum = 0.f, ss = 0.f;
#pragma unroll
        for (int c = 0; c < 4; c++) {
            float4 f = *(const float4*)&xr[c * 256 + t * 4];
            v[c * 4 + 0] = f.x; v[c * 4 + 1] = f.y; v[c * 4 + 2] = f.z; v[c * 4 + 3] = f.w;
            sum += f.x + f.y + f.z + f.w;
            ss += f.x * f.x + f.y * f.y + f.z * f.z + f.w * f.w;
        }
#pragma unroll
        for (int d = 32; d; d >>= 1) {
            sum += __shfl_xor(sum, d);
            ss  += __shfl_xor(ss, d);
        }
        float mu = sum * (1.f / E_);
        float var = ss * (1.f / E_) - mu * mu;
        float rs = rsqrtf(var + 1e-5f);
#pragma unroll
        for (int c = 0; c < 4; c++) {
            int idx = c * 256 + t * 4;
            float4 g4 = *(const float4*)&g1[idx];
            float4 b4 = *(const float4*)&b1v[idx];
            ushort4 o;
            o.x = f2b((v[c * 4 + 0] - mu) * rs * g4.x + b4.x);
            o.y = f2b((v[c * 4 + 1] - mu) * rs * g4.y + b4.y);
            o.z = f2b((v[c * 4 + 2] - mu) * rs * g4.z + b4.z);
            o.w = f2b((v[c * 4 + 3] - mu) * rs * g4.w + b4.w);
            *(ushort4*)&hB[(size_t)row * E_ + idx] = o;
        }
        return;
    }
    int i = (blockIdx.x - 1024) * 256 + threadIdx.x;
    if (i >= 3146496) return;
    if (i >= 3145728) {             // biases (fp32 copy)
        int j = i - 3145728;        // 0..767
        const float* s = (j < 256) ? bq : (j < 512) ? bk : bv;
        int jj = j & 255;
        *(float4*)&bqkv[j * 4] = *(const float4*)&s[jj * 4];
        return;
    }
    const float* src; u16* dst; int j;
    if (i < 786432) {
        src = (i < 262144) ? Wq : (i < 524288) ? Wk : Wv;
        j = i & 262143;
        dst = WqkvB + (i >> 18) * (E_ * E_);
    } else if (i < 1048576) { j = i - 786432;  src = Wo; dst = WoB; }
    else if (i < 2097152)   { j = i - 1048576; src = W1; dst = W1B; }
    else                    { j = i - 2097152; src = W2; dst = W2B; }
    float4 f = *(const float4*)&src[j * 4];
    ushort4 o;
    o.x = f2b(f.x); o.y = f2b(f.y); o.z = f2b(f.z); o.w = f2b(f.w);
    *(ushort4*)&dst[j * 4] = o;
}

// ---------------- LayerNorm: 1 wave per row of 1024 ----------------
__global__ __launch_bounds__(64) void ln_fwd(u16* __restrict__ out, const float* __restrict__ x,
                                             const float* __restrict__ g, const float* __restrict__ bta) {
    int row = blockIdx.x;
    int t = threadIdx.x;
    const float* xr = x + (size_t)row * E_;
    float v[16];
    float sum = 0.f, ss = 0.f;
#pragma unroll
    for (int c = 0; c < 4; c++) {
        float4 f = *(const float4*)&xr[c * 256 + t * 4];
        v[c * 4 + 0] = f.x; v[c * 4 + 1] = f.y; v[c * 4 + 2] = f.z; v[c * 4 + 3] = f.w;
        sum += f.x + f.y + f.z + f.w;
        ss += f.x * f.x + f.y * f.y + f.z * f.z + f.w * f.w;
    }
#pragma unroll
    for (int d = 32; d; d >>= 1) {
        sum += __shfl_xor(sum, d);
        ss  += __shfl_xor(ss, d);
    }
    float mu = sum * (1.f / E_);
    float var = ss * (1.f / E_) - mu * mu;
    float rs = rsqrtf(var + 1e-5f);
#pragma unroll
    for (int c = 0; c < 4; c++) {
        int idx = c * 256 + t * 4;
        float4 g4 = *(const float4*)&g[idx];
        float4 b4 = *(const float4*)&bta[idx];
        ushort4 o;
        o.x = f2b((v[c * 4 + 0] - mu) * rs * g4.x + b4.x);
        o.y = f2b((v[c * 4 + 1] - mu) * rs * g4.y + b4.y);
        o.z = f2b((v[c * 4 + 2] - mu) * rs * g4.z + b4.z);
        o.w = f2b((v[c * 4 + 3] - mu) * rs * g4.w + b4.w);
        *(ushort4*)&out[(size_t)row * E_ + idx] = o;
    }
}

// ---------------- bf16 MFMA GEMM (m97 structure, BUFS-parameterized) ----------------
// C[M,N] = A[M,K] * Bt[N,K]^T. BMxBN tile, 256 thr (2x2 waves), BK=32.
// BUFS=2: exact m97/R0 structure — __syncthreads (compiler vmcnt(0)+barrier drain),
//   LDS 2x(BM+BN)x32x2B = 32KB at 128x128 -> 4 blocks/CU -> 1024 resident slots.
//   Grids are sized to ONE generation (1024 blocks max) — the R3 FF1 defect was
//   1024 blocks over 768 slots (3-stage, 48KB) = 1.33 gens with a 1/3-speed tail.
// BUFS=3: counted-vmcnt 3-stage (kept for reference/small-K call sites).
// Split-K (oP1 != null): kz0 -> outF (acc+bias+residual); kz>=1 -> raw acc into
// oP1/oP2/oP3. swz: XCD-chunked blockIdx remap (T1) for per-XCD L2 reuse.
template<int BM, int BN, int BUFS>
__global__ __launch_bounds__(256) void gemm_bt(
        const u16* __restrict__ A, const u16* __restrict__ Bt,
        const float* __restrict__ bias, const float* __restrict__ residual,
        float* __restrict__ outF, float* __restrict__ oP1,
        float* __restrict__ oP2, float* __restrict__ oP3,
        u16* __restrict__ outB, u16* __restrict__ outVt,
        int M, int N, int K, int ldk, int relu, int qkvmode, int swz) {
    constexpr int MT = BM / 32, NT = BN / 32;
    constexpr int LA = BM / 64, LB = BN / 64;   // gl16 issues per wave per K-step
    __shared__ __align__(16) u16 As[BUFS][BM * 32];
    __shared__ __align__(16) u16 Bs[BUFS][BN * 32];
    int tid = threadIdx.x;
    int bx = blockIdx.x, by = blockIdx.y;
    if (swz) {
        int gx = gridDim.x;
        int nwg = gx * gridDim.y;
        int lin = by * gx + bx;
        int wv = (lin & 7) * (nwg >> 3) + (lin >> 3);
        bx = wv % gx; by = wv / gx;
    }
    int m0 = by * BM, n0 = bx * BN;
    int kz = blockIdx.z;
    int koff = kz * K;
    int wave = tid >> 6, lane = tid & 63;
    int wm = wave & 1, wn = wave >> 1;
    int r16 = lane & 15, kg = lane >> 4;

    const u16* gA = A + (size_t)(m0 + wave * (BM / 4) + (lane >> 2)) * ldk + koff + (lane & 3) * 8;
    const u16* gB = Bt + (size_t)(n0 + wave * (BN / 4) + (lane >> 2)) * ldk + koff + (lane & 3) * 8;
    size_t row16 = (size_t)16 * ldk;
    int aoff = wave * (BM / 4) * 32;
    int boff = wave * (BN / 4) * 32;

    f32x4 acc[MT][NT] = {};

    const int nk = K >> 5;

    auto issue = [&](int kt, int buf) {
        int k1 = kt << 5;
        gl16(gA + k1, As[buf] + aoff);
        if (LA == 2) gl16(gA + k1 + row16, As[buf] + aoff + 512);
        gl16(gB + k1, Bs[buf] + boff);
        if (LB == 2) gl16(gB + k1 + row16, Bs[buf] + boff + 512);
    };

    auto compute = [&](int cb) {
        bf16x8 af[MT], bfr[NT];
#pragma unroll
        for (int mt = 0; mt < MT; mt++)
            af[mt] = *(const bf16x8*)&As[cb][(wm * (BM / 2) + mt * 16 + r16) * 32 + kg * 8];
#pragma unroll
        for (int nt = 0; nt < NT; nt++)
            bfr[nt] = *(const bf16x8*)&Bs[cb][(wn * (BN / 2) + nt * 16 + r16) * 32 + kg * 8];
#pragma unroll
        for (int mt = 0; mt < MT; mt++)
#pragma unroll
            for (int nt = 0; nt < NT; nt++)
                acc[mt][nt] = __builtin_amdgcn_mfma_f32_16x16x32_bf16(af[mt], bfr[nt], acc[mt][nt], 0, 0, 0);
    };

    if constexpr (BUFS == 2) {
        // m97 structure: single __syncthreads per K-step; loads for ks+1 issued
        // after the barrier into the buffer read at ks-1 (safe: its readers'
        // ds_reads completed before their MFMAs, which precede this barrier).
        issue(0, 0);
        for (int ks = 0; ks < nk; ks++) {
            __syncthreads();
            if (ks + 1 < nk) issue(ks + 1, (ks + 1) & 1);
            compute(ks & 1);
        }
    } else {
        issue(0, 0);
        issue(1, 1);
        int cur = 0;
        for (int ks = 0; ks < nk - 1; ks++) {
            wait_vmcnt<LA + LB>();
            __builtin_amdgcn_s_barrier();
            asm volatile("" ::: "memory");
            if (ks + 2 < nk) {
                int p2 = cur ? cur - 1 : 2;
                issue(ks + 2, p2);
            }
            compute(cur);
            cur = (cur < 2) ? cur + 1 : 0;
        }
        asm volatile("s_waitcnt vmcnt(0)" ::: "memory");
        __builtin_amdgcn_s_barrier();
        asm volatile("" ::: "memory");
        compute(cur);
    }

#pragma unroll
    for (int mt = 0; mt < MT; mt++) {
#pragma unroll
        for (int nt = 0; nt < NT; nt++) {
            int gm = m0 + wm * (BM / 2) + mt * 16 + kg * 4;
            int gn = n0 + wn * (BN / 2) + nt * 16 + r16;
            float bv = bias[gn];
            if (qkvmode) {
                if (gn < 2048) {
                    // Q prescale: 1/sqrt(64) * log2(e)  (attn softmax runs in exp2 domain)
                    float scl = (gn < 1024) ? 0.18033688f : 1.0f;
#pragma unroll
                    for (int r = 0; r < 4; r++)
                        outB[(size_t)(gm + r) * 2048 + gn] = f2b((acc[mt][nt][r] + bv) * scl);
                } else {
                    int bq_ = gm >> 11, tq = gm & 2047, d = gn - 2048;
                    ushort4 ov;
                    ov.x = f2b(acc[mt][nt][0] + bv);
                    ov.y = f2b(acc[mt][nt][1] + bv);
                    ov.z = f2b(acc[mt][nt][2] + bv);
                    ov.w = f2b(acc[mt][nt][3] + bv);
                    *(ushort4*)&outVt[((size_t)(bq_ * 1024 + d)) * 2048 + tq] = ov;
                }
            } else if (oP1) {                // split-K partials (fp32)
                float* po = (kz == 1) ? oP1 : (kz == 2) ? oP2 : oP3;
#pragma unroll
                for (int r = 0; r < 4; r++) {
                    size_t off = (size_t)(gm + r) * N + gn;
                    if (kz == 0) {
                        float v = acc[mt][nt][r] + bv;
                        if (residual) v += residual[off];
                        outF[off] = v;
                    } else {
                        po[off] = acc[mt][nt][r];
                    }
                }
            } else {
#pragma unroll
                for (int r = 0; r < 4; r++) {
                    float v = acc[mt][nt][r] + bv;
                    size_t off = (size_t)(gm + r) * N + gn;
                    if (residual) v += residual[off];
                    if (relu) v = fmaxf(v, 0.f);
                    if (outF) outF[off] = v;
                    else outB[off] = f2b(v);
                }
            }
        }
    }
}

// split-K combine: d += a + b + c  (bias+residual already folded into d by kz0 pass)
__global__ __launch_bounds__(256) void addf3(float* __restrict__ d, const float* __restrict__ a,
                                             const float* __restrict__ b, const float* __restrict__ c) {
    size_t i = ((size_t)blockIdx.x * 256 + threadIdx.x) * 4;
    float4 vd = *(float4*)&d[i];
    float4 va = *(const float4*)&a[i];
    float4 vb = *(const float4*)&b[i];
    float4 vc = *(const float4*)&c[i];
    vd.x += va.x + vb.x + vc.x;
    vd.y += va.y + vb.y + vc.y;
    vd.z += va.z + vb.z + vc.z;
    vd.w += va.w + vb.w + vc.w;
    *(float4*)&d[i] = vd;
}

// ---------------- MFMA flash attention (bf16, causal, FIXED-SHIFT exp2 softmax) -----
#define AST 68   // 34 dw stride: bank-conflict-free for all access patterns here
__global__ __launch_bounds__(256) void attn_mfma(
        const u16* __restrict__ qk, const u16* __restrict__ vt,
        u16* __restrict__ out) {
    __shared__ __align__(16) u16 Ks[2][64 * AST];  // K[key][d]
    __shared__ __align__(16) u16 Vs[2][64 * AST];  // Vt[d][key]
    __shared__ __align__(16) u16 Ps[4][16 * AST];  // per-wave P[q][key]

    int bz = blockIdx.x;
    int h  = bz & 15;
    int b  = (bz >> 4) & 1;
    int qt = bz >> 5;

    int tid = threadIdx.x;
    int w = tid >> 6, lane = tid & 63;
    int g = lane >> 4, l16 = lane & 15;

    int qrow = qt * 64 + w * 16 + l16;
    bf16x8 qf[2];
    qf[0] = *(const bf16x8*)&qk[(size_t)(b * T_ + qrow) * 2048 + h * 64 + g * 8];
    qf[1] = *(const bf16x8*)&qk[(size_t)(b * T_ + qrow) * 2048 + h * 64 + 32 + g * 8];

    f32x4 o[4] = {};
    f32x4 lp = {0.f, 0.f, 0.f, 0.f};

    int r1 = tid >> 3, col1 = (tid & 7) * 8;
    const u16* gK = qk + (size_t)(b * T_) * 2048 + 1024 + h * 64;
    const u16* gV = vt + (size_t)(b * 1024 + h * 64) * 2048;

    uint4 kr1 = *(const uint4*)&gK[(size_t)r1 * 2048 + col1];
    uint4 kr2 = *(const uint4*)&gK[(size_t)(r1 + 32) * 2048 + col1];
    uint4 vr1 = *(const uint4*)&gV[(size_t)r1 * 2048 + col1];
    uint4 vr2 = *(const uint4*)&gV[(size_t)(r1 + 32) * 2048 + col1];

    for (int t = 0; t <= qt; t++) {
        int cur = t & 1;
        *(uint4*)&Ks[cur][r1 * AST + col1] = kr1;
        *(uint4*)&Ks[cur][(r1 + 32) * AST + col1] = kr2;
        *(uint4*)&Vs[cur][r1 * AST + col1] = vr1;
        *(uint4*)&Vs[cur][(r1 + 32) * AST + col1] = vr2;
        __syncthreads();
        if (t < qt) {
            int j1 = (t + 1) * 64;
            kr1 = *(const uint4*)&gK[(size_t)(j1 + r1) * 2048 + col1];
            kr2 = *(const uint4*)&gK[(size_t)(j1 + r1 + 32) * 2048 + col1];
            vr1 = *(const uint4*)&gV[(size_t)r1 * 2048 + j1 + col1];
            vr2 = *(const uint4*)&gV[(size_t)(r1 + 32) * 2048 + j1 + col1];
        }

        f32x4 s[4];
#pragma unroll
        for (int nt = 0; nt < 4; nt++) {
            f32x4 c16 = {-16.f, -16.f, -16.f, -16.f};
            bf16x8 k0 = *(const bf16x8*)&Ks[cur][(nt * 16 + l16) * AST + g * 8];
            bf16x8 k1 = *(const bf16x8*)&Ks[cur][(nt * 16 + l16) * AST + 32 + g * 8];
            s[nt] = __builtin_amdgcn_mfma_f32_16x16x32_bf16(qf[0], k0, c16, 0, 0, 0);
            s[nt] = __builtin_amdgcn_mfma_f32_16x16x32_bf16(qf[1], k1, s[nt], 0, 0, 0);
        }

        if (t == qt) {
            int j0 = t * 64;
#pragma unroll
            for (int nt = 0; nt < 4; nt++) {
                int key = j0 + nt * 16 + l16;
#pragma unroll
                for (int r = 0; r < 4; r++) {
                    int q = qt * 64 + w * 16 + g * 4 + r;
                    if (key > q) s[nt][r] = -INFINITY;
                }
            }
        }

#pragma unroll
        for (int nt = 0; nt < 4; nt++)
#pragma unroll
            for (int r = 0; r < 4; r++) {
                float p = exp2f(s[nt][r]);
                lp[r] += p;
                Ps[w][(g * 4 + r) * AST + nt * 16 + l16] = f2bt(p);
            }

#pragma unroll
        for (int kf = 0; kf < 2; kf++) {
            bf16x8 pf = *(const bf16x8*)&Ps[w][l16 * AST + kf * 32 + g * 8];
#pragma unroll
            for (int nt = 0; nt < 4; nt++) {
                bf16x8 vf = *(const bf16x8*)&Vs[cur][(nt * 16 + l16) * AST + kf * 32 + g * 8];
                o[nt] = __builtin_amdgcn_mfma_f32_16x16x32_bf16(pf, vf, o[nt], 0, 0, 0);
            }
        }
    }

#pragma unroll
    for (int x = 1; x <= 8; x <<= 1)
#pragma unroll
        for (int r = 0; r < 4; r++)
            lp[r] += __shfl_xor(lp[r], x);

    float inv[4];
#pragma unroll
    for (int r = 0; r < 4; r++) inv[r] = 1.f / lp[r];
    int qg = qt * 64 + w * 16 + g * 4;
#pragma unroll
    for (int nt = 0; nt < 4; nt++)
#pragma unroll
        for (int r = 0; r < 4; r++)
            out[(size_t)(b * T_ + qg + r) * E_ + h * 64 + nt * 16 + l16] =
                f2b(o[nt][r] * inv[r]);
}

extern "C" void kernel_launch(void* const* d_in, const int* in_sizes, int n_in,
                              void* d_out, int out_size, void* d_ws, size_t ws_size,
                              hipStream_t stream) {
    const float* x    = (const float*)d_in[0];
    const float* Wq   = (const float*)d_in[1];
    const float* bq   = (const float*)d_in[2];
    const float* Wk   = (const float*)d_in[3];
    const float* bk   = (const float*)d_in[4];
    const float* Wv   = (const float*)d_in[5];
    const float* bv   = (const float*)d_in[6];
    const float* Wo   = (const float*)d_in[7];
    const float* bo   = (const float*)d_in[8];
    const float* W1   = (const float*)d_in[9];
    const float* b1   = (const float*)d_in[10];
    const float* W2   = (const float*)d_in[11];
    const float* b2   = (const float*)d_in[12];
    const float* ln1g = (const float*)d_in[13];
    const float* ln1b = (const float*)d_in[14];
    const float* ln2g = (const float*)d_in[15];
    const float* ln2b = (const float*)d_in[16];

    char* ws = (char*)d_ws;
    size_t off = 0;
    auto alloc = [&](size_t bytes) { char* p = ws + off; off += (bytes + 255) & ~(size_t)255; return p; };

    u16*   hB    = (u16*)  alloc((size_t)M_ * E_ * 2);        // LN1 out bf16
    u16*   WqkvB = (u16*)  alloc((size_t)3 * E_ * E_ * 2);    // packed q,k,v weights bf16
    u16*   WoB   = (u16*)  alloc((size_t)E_ * E_ * 2);
    u16*   W1B   = (u16*)  alloc((size_t)FF_ * E_ * 2);
    u16*   W2B   = (u16*)  alloc((size_t)E_ * FF_ * 2);
    float* bqkv  = (float*)alloc(3 * E_ * 4);
    u16*   qkB   = (u16*)  alloc((size_t)M_ * 2 * E_ * 2);    // bf16 [M,2048], Q prescaled
    u16*   vtG   = (u16*)  alloc((size_t)M_ * E_ * 2);        // bf16 V^T [B*1024, 2048]
    u16*   attnB = (u16*)  alloc((size_t)M_ * E_ * 2);        // attention out bf16
    float* x2    = (float*)alloc((size_t)M_ * E_ * 4);        // after out-proj + residual
    u16*   h2B   = (u16*)  alloc((size_t)M_ * E_ * 2);        // LN2 out bf16
    u16*   rB    = (u16*)  alloc((size_t)M_ * FF_ * 2);       // relu(ff1) bf16
    float* P1    = (float*)alloc((size_t)M_ * E_ * 4);        // FF2 split-K partial (kz=1)
    // kz=2,3 partials alias workspace that is dead by FF2 time:
    float* P2 = (float*)qkB;    // 16 MB, dead after attn
    float* P3 = (float*)ws;     // hB+WqkvB+WoB = 16 MB, dead after Wo-proj

    // fused weight/bias conversion + LN1 (one launch)
    cvt_ln<<<1024 + 12291, 256, 0, stream>>>(Wq, Wk, Wv, Wo, W1, W2, bq, bk, bv,
                                             WqkvB, WoB, W1B, W2B, bqkv,
                                             x, ln1g, ln1b, hB);

    // fused QKV projection: [4096,1024] x [3072,1024]^T  (768 blocks, 4/CU, 1 gen)
    gemm_bt<128, 128, 2><<<dim3(3 * E_ / 128, M_ / 128), 256, 0, stream>>>(
        hB, WqkvB, bqkv, nullptr, nullptr, nullptr, nullptr, nullptr, qkB, vtG,
        M_, 3 * E_, E_, E_, 0, 1, 0);

    // flash attention
    attn_mfma<<<B_ * H_ * (T_ / 64), 256, 0, stream>>>(qkB, vtG, attnB);

    // out projection + residual: x2 = x + attn @ Wo^T + bo  (512 blocks, 6/CU cap)
    gemm_bt<64, 128, 2><<<dim3(E_ / 128, M_ / 64), 256, 0, stream>>>(
        attnB, WoB, bo, x, x2, nullptr, nullptr, nullptr, nullptr, nullptr,
        M_, E_, E_, E_, 0, 0, 0);

    // LN2
    ln_fwd<<<M_, 64, 0, stream>>>(h2B, x2, ln2g, ln2b);

    // FF1 + relu -> bf16  (1024 blocks = 4/CU, exactly ONE generation, XCD swizzle)
    gemm_bt<128, 128, 2><<<dim3(FF_ / 128, M_ / 128), 256, 0, stream>>>(
        h2B, W1B, b1, nullptr, nullptr, nullptr, nullptr, nullptr, rB, nullptr,
        M_, FF_, E_, E_, 1, 0, 1);

    // FF2 split-K=4 at 128x128: grid (8,32,4) = 1024 blocks = 4/CU, one generation,
    // K=1024 each (ldk=4096). kz0 -> d_out (acc+bias+residual), kz1..3 -> P1..P3.
    gemm_bt<128, 128, 2><<<dim3(E_ / 128, M_ / 128, 4), 256, 0, stream>>>(
        rB, W2B, b2, x2, (float*)d_out, P1, P2, P3, nullptr, nullptr,
        M_, E_, FF_ / 4, FF_, 0, 0, 1);

    // combine: d_out += P1 + P2 + P3  (16MB fp32 x 5 streams)
    addf3<<<(M_ * E_) / (256 * 4), 256, 0, stream>>>((float*)d_out, P1, P2, P3);
}